// Round 1
// 136.587 us; speedup vs baseline: 1.1679x; 1.1679x over previous
//
#include <hip/hip_runtime.h>

#define CCH 16
#define DD 64
#define HH 96
#define WW 96
#define HW (HH*WW)
#define DHW (DD*HH*WW)   // 589824
#define CH4 (DHW/4)      // 147456
#define NTH 768          // 16 lh x 48 lc, 2 w-sites per thread
#define DCH 16           // depth outputs per block
#define NBY (DD/DCH)     // 4 depth chunks
#define KTR 1.08f        // 27 * k_harris (S unscaled by 1/27; ranking-invariant)
#define INV27C (1.f/19683.f)

typedef float v2f __attribute__((ext_vector_type(2)));

// DPP row16 shifts: thread layout is lh-fast (lh = tid & 15), so a DPP row of
// 16 lanes == one h-column; bound_ctrl=true zero-fills at row ends (filled
// sites only feed non-emitted outputs). Harris is invariant to an up/down swap
// (every term has even degree in each gradient; a swap only flips gy's sign).
__device__ __forceinline__ float dpp_up(float v) {
    return __int_as_float(__builtin_amdgcn_update_dpp(
        0, __float_as_int(v), 0x111 /*row_shr:1*/, 0xF, 0xF, true));
}
__device__ __forceinline__ float dpp_dn(float v) {
    return __int_as_float(__builtin_amdgcn_update_dpp(
        0, __float_as_int(v), 0x101 /*row_shl:1*/, 0xF, 0xF, true));
}

// R12: barrier-free main loop. The w-halo gradients (sites w-1, w+2) are
// recomputed LOCALLY from a 6-wide x window (float2 at w-2, w, w+2) instead of
// being exchanged through LDS -> the 6w+6r LDS traffic and the per-slice
// __syncthreads are gone entirely (LDS: 37 KB -> 48 B). Halo expressions use
// the exact association order the neighbor thread used -> bit-identical.
// Depth loads are software-pipelined one slice ahead (prefetch e+2 while
// computing e), and the 18-iteration loop is fully unrolled so window/field
// pipeline rotation becomes register renaming.
__global__ __launch_bounds__(NTH, 6)
void harris_sum_kernel(const float* __restrict__ x, float* __restrict__ pp) {
    __shared__ float red[12];

    const int tid = threadIdx.x;
    const int lh = tid & 15, lc = tid >> 4;   // lc 0..47
    const int c  = blockIdx.z;
    const int H0 = blockIdx.x * 12;
    const int o0 = blockIdx.y * DCH;
    const int gh = H0 + lh - 2;
    const bool rowok = ((unsigned)gh < HH);
    const float mask = rowok ? 1.f : 0.f;     // zero products at OOB rows (box zero-pad)
    const bool lok = (lc > 0), rok = (lc < 47);
    const float maskl = lok ? mask : 0.f;     // w-edge zero-pad folded into row mask
    const float maskr = rok ? mask : 0.f;
    const float* xc = x + (size_t)c * DHW;
    const int woff = gh * WW + (lc << 1);

    // x window: slices e-1(p), e(m), e+1(n), prefetch e+2(f);
    // per slice: L = x[w-2..w-1], C = x[w..w+1], R = x[w+2..w+3]
    v2f Lp,Cp,Rp, Lm,Cm,Rm, Ln,Cn,Rn, Lf,Cf,Rf;

    auto loadslice = [&](int e, v2f& L, v2f& C, v2f& R) {
        if (rowok && (unsigned)e < DD) {
            const float* s = xc + (size_t)e * HW + woff;
            const float2 t = *(const float2*)s;
            C.x = t.x; C.y = t.y;
            if (lok) { const float2 u = *(const float2*)(s - 2); L.x = u.x; L.y = u.y; }
            else     { L.x = 0.f; L.y = 0.f; }
            if (rok) { const float2 u = *(const float2*)(s + 2); R.x = u.x; R.y = u.y; }
            else     { R.x = 0.f; R.y = 0.f; }
        } else {
            L.x=0.f; L.y=0.f; C.x=0.f; C.y=0.f; R.x=0.f; R.y=0.f;
        }
    };

    loadslice(o0 - 2, Lp, Cp, Rp);
    loadslice(o0 - 1, Lm, Cm, Rm);
    loadslice(o0,     Ln, Cn, Rn);

    v2f s2m1[6], s2m2[6];
    #pragma unroll
    for (int f = 0; f < 6; ++f) {
        s2m1[f].x = 0.f; s2m1[f].y = 0.f;
        s2m2[f].x = 0.f; s2m2[f].y = 0.f;
    }
    v2f hv; hv.x = 0.f; hv.y = 0.f;
    const bool emit_row = (lh >= 2) && (lh <= 13);

    #pragma unroll
    for (int k = 0; k < DCH + 2; ++k) {       // 18 slices -> 16 output slices
        const int e = o0 - 1 + k;
        if (k <= DCH) loadslice(e + 2, Lf, Cf, Rf);   // prefetch next-next slice
        else { Lf.x=0.f;Lf.y=0.f; Cf.x=0.f;Cf.y=0.f; Rf.x=0.f;Rf.y=0.f; }

        v2f s2c[6];
        if ((unsigned)e < DD) {               // block-uniform branch
            const v2f AL = (Lp + Lm) + Ln;    // depth [1,1,1] (pk)
            const v2f AC = (Cp + Cm) + Cn;
            const v2f AR = (Rp + Rm) + Rn;
            const v2f DL = Ln - Lp;           // depth [-1,0,1] (pk)
            const v2f DC = Cn - Cp;
            const v2f DR = Rn - Rp;

            // w-convs at 4 sites: l = w-1 (halo), 0 = w, 1 = w+1, r = w+2 (halo)
            const float Sxl = AC.x - AL.x, Sx0 = AC.y - AL.y,
                        Sx1 = AR.x - AC.x, Sxr = AR.y - AC.y;
            const float Txl = AL.x + 2.f*AL.y + AC.x, Tx0 = AL.y + 2.f*AC.x + AC.y,
                        Tx1 = AC.x + 2.f*AC.y + AR.x, Txr = AC.y + 2.f*AR.x + AR.y;
            const float Tdl = DL.x + DL.y + DC.x, Td0 = DL.y + DC.x + DC.y,
                        Td1 = DC.x + DC.y + DR.x, Tdr = DC.y + DR.x + DR.y;

            // h-convs via DPP (VALU pipe) — halo gradients computed locally,
            // bit-identical to what the neighbor thread would have exchanged
            const float glx = (dpp_up(Sxl) + 2.f*Sxl + dpp_dn(Sxl)) * maskl;
            const float gly = (dpp_dn(Txl) - dpp_up(Txl)) * maskl;
            const float glz = (dpp_up(Tdl) + Tdl + dpp_dn(Tdl)) * maskl;
            const float gx0 = (dpp_up(Sx0) + 2.f*Sx0 + dpp_dn(Sx0)) * mask;
            const float gy0 = (dpp_dn(Tx0) - dpp_up(Tx0)) * mask;
            const float gz0 = (dpp_up(Td0) + Td0 + dpp_dn(Td0)) * mask;
            const float gx1 = (dpp_up(Sx1) + 2.f*Sx1 + dpp_dn(Sx1)) * mask;
            const float gy1 = (dpp_dn(Tx1) - dpp_up(Tx1)) * mask;
            const float gz1 = (dpp_up(Td1) + Td1 + dpp_dn(Td1)) * mask;
            const float grx = (dpp_up(Sxr) + 2.f*Sxr + dpp_dn(Sxr)) * maskr;
            const float gry = (dpp_dn(Txr) - dpp_up(Txr)) * maskr;
            const float grz = (dpp_up(Tdr) + Tdr + dpp_dn(Tdr)) * maskr;

            // products: own pair packed, halo scalar
            v2f gxv, gyv, gzv;
            gxv.x = gx0; gxv.y = gx1; gyv.x = gy0; gyv.y = gy1; gzv.x = gz0; gzv.y = gz1;
            const v2f Pxx = gxv*gxv, Pyy = gyv*gyv, Pzz = gzv*gzv;
            const v2f Pxy = gxv*gyv, Pxz = gxv*gzv, Pyz = gyv*gzv;
            const float Plxx = glx*glx, Plyy = gly*gly, Plzz = glz*glz;
            const float Plxy = glx*gly, Plxz = glx*glz, Plyz = gly*glz;
            const float Prxx = grx*grx, Pryy = gry*gry, Przz = grz*grz;
            const float Prxy = grx*gry, Prxz = grx*grz, Pryz = gry*grz;

            // w [1,1,1] on products + h [1,1,1] via DPP
            #define FIELD(f, Pv, Pl, Pr)                                   \
            {   const float s_ = (Pv).x + (Pv).y;                          \
                const float R0 = (Pl) + s_, R1 = s_ + (Pr);                \
                s2c[f].x = dpp_up(R0) + R0 + dpp_dn(R0);                   \
                s2c[f].y = dpp_up(R1) + R1 + dpp_dn(R1); }
            FIELD(0, Pxx, Plxx, Prxx)
            FIELD(1, Pyy, Plyy, Pryy)
            FIELD(2, Pzz, Plzz, Przz)
            FIELD(3, Pxy, Plxy, Prxy)
            FIELD(4, Pxz, Plxz, Prxz)
            FIELD(5, Pyz, Plyz, Pryz)
            #undef FIELD
        } else {
            #pragma unroll
            for (int f = 0; f < 6; ++f) { s2c[f].x = 0.f; s2c[f].y = 0.f; }
        }

        if (k >= 2 && emit_row) {   // emit output slice o = e-1 (packed math)
            const v2f sxx = s2m2[0] + s2m1[0] + s2c[0];
            const v2f syy = s2m2[1] + s2m1[1] + s2c[1];
            const v2f szz = s2m2[2] + s2m1[2] + s2c[2];
            const v2f sxy = s2m2[3] + s2m1[3] + s2c[3];
            const v2f sxz = s2m2[4] + s2m1[4] + s2c[4];
            const v2f syz = s2m2[5] + s2m1[5] + s2c[5];
            const v2f det = sxx*(syy*szz - syz*syz)
                          - sxy*(sxy*szz - syz*sxz)
                          + sxz*(sxy*syz - syy*sxz);
            const v2f tr = sxx + syy + szz;
            hv += det - KTR * (tr * tr);   // unscaled by 27^-3: ranking-invariant
        }
        #pragma unroll
        for (int f = 0; f < 6; ++f) { s2m2[f] = s2m1[f]; s2m1[f] = s2c[f]; }
        Lp = Lm; Cp = Cm; Rp = Rm;
        Lm = Ln; Cm = Cn; Rm = Rn;
        Ln = Lf; Cn = Cf; Rn = Rf;
    }

    float hs = hv.x + hv.y;
    // block reduce -> per-block partial slot (no atomics, no ws init needed)
    #pragma unroll
    for (int o = 32; o > 0; o >>= 1) hs += __shfl_down(hs, o, 64);
    if ((tid & 63) == 0) red[tid >> 6] = hs;
    __syncthreads();
    if (tid == 0) {
        float s = 0.f;
        #pragma unroll
        for (int i = 0; i < 12; ++i) s += red[i];
        pp[c * 32 + blockIdx.y * 8 + blockIdx.x] = s * INV27C;
    }
}

// Sum 32 partials/channel, top-8 select via parallel rank (equivalent to the
// serial strict-> scan: rank = #{bigger} + #{equal with smaller index}),
// then gather copy.
__global__ __launch_bounds__(256)
void gather_topk_kernel(const float* __restrict__ x, const float* __restrict__ pp,
                        float4* __restrict__ out) {
    __shared__ float pv[CCH];
    __shared__ int sidx[8];
    const int tid = threadIdx.x;
    if (tid < CCH) {
        float s = 0.f;
        #pragma unroll
        for (int j = 0; j < 32; ++j) s += pp[tid * 32 + j];
        pv[tid] = s;   // fixed order -> deterministic across blocks
    }
    __syncthreads();
    if (tid < CCH) {
        const float v = pv[tid];
        int r = 0;
        #pragma unroll
        for (int i = 0; i < CCH; ++i) {
            const float u = pv[i];
            r += (u > v) || (u == v && i < tid);
        }
        if (r < 8) sidx[r] = tid;
    }
    __syncthreads();
    const int j   = blockIdx.y;                      // 0..7
    const int pos = blockIdx.x * 256 + tid;          // 576*256 == CH4 exact
    const int cidx = sidx[j];
    const float4* src = (const float4*)(x + (size_t)cidx * DHW);
    out[(size_t)j * CH4 + pos] = src[pos];
}

extern "C" void kernel_launch(void* const* d_in, const int* in_sizes, int n_in,
                              void* d_out, int out_size, void* d_ws, size_t ws_size,
                              hipStream_t stream) {
    const float* x = (const float*)d_in[0];
    float4* out = reinterpret_cast<float4*>(d_out);
    float* pp = (float*)d_ws;                        // 512 per-block partials (2 KB)

    dim3 g1(8, NBY, CCH);                            // (8,4,16) = 512 blocks
    harris_sum_kernel<<<g1, NTH, 0, stream>>>(x, pp);

    dim3 g2(CH4 / 256, 8, 1);                        // (576, 8)
    gather_topk_kernel<<<g2, 256, 0, stream>>>(x, pp, out);
}